// Round 4
// baseline (100.321 us; speedup 1.0000x reference)
//
#include <hip/hip_runtime.h>
#include <hip/hip_bf16.h>
#include <math.h>

#define N 4096
#define PB 32   // prep blocks / partial slots

typedef __attribute__((ext_vector_type(8))) short short8;
typedef __attribute__((ext_vector_type(4))) float floatx4;

// ws layout (floats): P[b*66 + d], b<32: d<64 = column-sum partials, [64] = sum(x^2) partial

__device__ inline unsigned bfpk(float a, float b) {
    unsigned ua = __float_as_uint(a), ub = __float_as_uint(b);
    ua = (ua + 0x7fffu + ((ua >> 16) & 1u)) >> 16;   // RNE fp32->bf16
    ub = (ub + 0x7fffu + ((ub >> 16) & 1u)) >> 16;
    return ua | (ub << 16);
}

__device__ inline uint4 pack8(float4 f0, float4 f1) {
    uint4 r;
    r.x = bfpk(f0.x, f0.y);
    r.y = bfpk(f0.z, f0.w);
    r.z = bfpk(f1.x, f1.y);
    r.w = bfpk(f1.z, f1.w);
    return r;
}

// ---------- prep: per-block partial column-sums + sum(x^2). No atomics, no init. ----------
__global__ __launch_bounds__(256) void prep_kernel(const float* __restrict__ X,
                                                   float* __restrict__ ws) {
    __shared__ float sm[256];
    __shared__ float ssum[4];
    const int lane = threadIdx.x & 63, w = threadIdx.x >> 6;
    const int b = blockIdx.x;
    const int row0 = b * 128 + w * 32;             // 32 rows per wave, 128 per block
    float mloc = 0.f, Sloc = 0.f;
    #pragma unroll
    for (int rr = 0; rr < 32; ++rr) {
        float x = X[(size_t)(row0 + rr) * 64 + lane];   // lane = column, coalesced
        mloc += x; Sloc += x * x;
    }
    sm[threadIdx.x] = mloc;
    #pragma unroll
    for (int off = 1; off < 64; off <<= 1) Sloc += __shfl_xor(Sloc, off, 64);
    if (lane == 0) ssum[w] = Sloc;
    __syncthreads();
    if (threadIdx.x < 64) {
        ws[b * 66 + threadIdx.x] =
            sm[threadIdx.x] + sm[64 + threadIdx.x] + sm[128 + threadIdx.x] + sm[192 + threadIdx.x];
    } else if (threadIdx.x == 64) {
        ws[b * 66 + 64] = ssum[0] + ssum[1] + ssum[2] + ssum[3];
    }
}

// ---------------- main: symmetric MFMA gram + fused RBF epilogue, 1024 blocks ----------------
// b < 32:            diagonal FULL tile d=b (two 16-row strips per wave, sequential; direct
//                    stores only; 64 KB stored — same bytes as an off-diag half-block).
// b >= 32:           off-diag upper-tri pair t=(b-32)>>1, half h=(b-32)&1; direct (I,J) +
//                    float4 transposed (J,I) stores.
// LDS: slot(r,c) = 8*r + (c ^ (r&7)); fragment ds_read_b128 lands 2-way (free, m136).
__global__ __launch_bounds__(256, 4) void rbf_kernel(const float* __restrict__ X,
                                                     const float* __restrict__ ws,
                                                     float* __restrict__ out) {
    __shared__ uint4 lA[512];    // 8 KB: 64 rows (off-diag I-half)
    __shared__ uint4 lB[1024];   // 16 KB: 128 rows (J-tile / diag tile)
    __shared__ float sR[64];
    __shared__ float sC[128];

    const int t_ = threadIdx.x;
    const int b  = blockIdx.x;

    const bool diag = (b < 32);
    int I, J, h;
    if (diag) {
        I = J = b; h = 0;
    } else {
        int t = (b - 32) >> 1; h = (b - 32) & 1;
        int i = (int)((63.0f - sqrtf((float)(3969 - 8 * t))) * 0.5f);
        while (31 * (i + 1) - ((i + 1) * i) / 2 <= t) ++i;
        while (31 * i - (i * (i - 1)) / 2 > t) --i;
        int oi = 31 * i - (i * (i - 1)) / 2;
        I = i; J = i + 1 + (t - oi);
    }
    const int rowBase = I * 128 + h * 64;
    const int colBase = J * 128;

    // ---- stage fp32 -> bf16 into swizzled LDS; fold row norms in ----
    #pragma unroll
    for (int i = 0; i < 4; ++i) {       // J-tile: 128 rows
        int slot = i * 256 + t_;
        int r = slot >> 3, g = slot & 7;
        int c = g ^ (r & 7);
        const float4* p = (const float4*)(X + (size_t)(colBase + r) * 64 + c * 8);
        float4 f0 = p[0], f1 = p[1];
        lB[slot] = pack8(f0, f1);
        float nb = f0.x*f0.x + f0.y*f0.y + f0.z*f0.z + f0.w*f0.w
                 + f1.x*f1.x + f1.y*f1.y + f1.z*f1.z + f1.w*f1.w;
        #pragma unroll
        for (int off = 1; off < 8; off <<= 1) nb += __shfl_xor(nb, off, 64);
        if (g == 0) sC[r] = nb;
    }
    if (!diag) {
        #pragma unroll
        for (int i = 0; i < 2; ++i) {   // I-half: 64 rows
            int slot = i * 256 + t_;
            int r = slot >> 3, g = slot & 7;
            int c = g ^ (r & 7);
            const float4* p = (const float4*)(X + (size_t)(rowBase + r) * 64 + c * 8);
            float4 f0 = p[0], f1 = p[1];
            lA[slot] = pack8(f0, f1);
            float na = f0.x*f0.x + f0.y*f0.y + f0.z*f0.z + f0.w*f0.w
                     + f1.x*f1.x + f1.y*f1.y + f1.z*f1.z + f1.w*f1.w;
            #pragma unroll
            for (int off = 1; off < 8; off <<= 1) na += __shfl_xor(na, off, 64);
            if (g == 0) sR[r] = na;
        }
    }
    __syncthreads();

    // ---- bw from prep partials (L2-resident 8.4 KB; overlaps fragment loads) ----
    const int lane = t_ & 63;
    float mv = 0.f;
    #pragma unroll 8
    for (int pb = 0; pb < PB; ++pb) mv += ws[pb * 66 + lane];
    float Sv = (lane < PB) ? ws[lane * 66 + 64] : 0.f;
    float mm = mv * mv;
    #pragma unroll
    for (int off = 1; off < 64; off <<= 1) {
        mm += __shfl_xor(mm, off, 64);
        Sv += __shfl_xor(Sv, off, 64);
    }
    float sumL2 = 2.0f * (float)N * Sv - 2.0f * mm;
    const float c1q = -1.4426950408889634f * 0.25f * (float)((size_t)N * N - N) / sumL2; // -log2e/(4*bw)

    const int wave = t_ >> 6;
    const int lr = lane & 15, q = lane >> 4;
    const int nStrips = diag ? 2 : 1;

    for (int s = 0; s < nStrips; ++s) {
        // strip rows (within 128-tile for diag, within 64-half for off-diag)
        const int rloc0 = s * 64 + wave * 16;

        int r1 = rloc0 + lr;
        short8 a0, a1;
        if (diag) {
            a0 = *reinterpret_cast<const short8*>(&lB[8 * r1 + ((q    ) ^ (r1 & 7))]);
            a1 = *reinterpret_cast<const short8*>(&lB[8 * r1 + ((q + 4) ^ (r1 & 7))]);
        } else {
            a0 = *reinterpret_cast<const short8*>(&lA[8 * r1 + ((q    ) ^ (r1 & 7))]);
            a1 = *reinterpret_cast<const short8*>(&lA[8 * r1 + ((q + 4) ^ (r1 & 7))]);
        }

        floatx4 acc[8];
        #pragma unroll
        for (int tj = 0; tj < 8; ++tj) acc[tj] = (floatx4){0.f, 0.f, 0.f, 0.f};

        #pragma unroll
        for (int tj = 0; tj < 8; ++tj) {
            int r2 = tj * 16 + lr;
            short8 b0 = *reinterpret_cast<const short8*>(&lB[8 * r2 + ((q    ) ^ (r2 & 7))]);
            short8 b1 = *reinterpret_cast<const short8*>(&lB[8 * r2 + ((q + 4) ^ (r2 & 7))]);
            acc[tj] = __builtin_amdgcn_mfma_f32_16x16x32_bf16(a0, b0, acc[tj], 0, 0, 0);
            acc[tj] = __builtin_amdgcn_mfma_f32_16x16x32_bf16(a1, b1, acc[tj], 0, 0, 0);
        }

        // ---- epilogue: u = t^(1/4) via ONE exp2; out = u^16+u^8+u^4+u^2+u ----
        // C layout (16x16x32): col = lane&15, row = (lane>>4)*4 + reg
        const int rb = rloc0 + q * 4;
        float sr0, sr1, sr2, sr3;
        if (diag) { sr0 = sC[rb]; sr1 = sC[rb+1]; sr2 = sC[rb+2]; sr3 = sC[rb+3]; }
        else      { sr0 = sR[rb]; sr1 = sR[rb+1]; sr2 = sR[rb+2]; sr3 = sR[rb+3]; }
        const size_t rowG = (size_t)(diag ? (I * 128) : rowBase) + rb;

        #pragma unroll
        for (int tj = 0; tj < 8; ++tj) {
            int cl = tj * 16 + lr;
            float scj = sC[cl];
            size_t col = (size_t)(colBase + cl);
            float4 tp;
            #pragma unroll
            for (int p = 0; p < 4; ++p) {
                float srp = (p == 0) ? sr0 : (p == 1) ? sr1 : (p == 2) ? sr2 : sr3;
                float d2 = srp + scj - 2.0f * acc[tj][p];
                d2 = fmaxf(d2, 0.0f);
                float u  = __builtin_amdgcn_exp2f(d2 * c1q);   // t^(1/4)
                float s1 = u * u;        // t^(1/2)
                float e  = s1 * s1;      // t
                float e2 = e * e;        // t^2
                float e4 = e2 * e2;      // t^4
                float val = e4 + e2 + e + s1 + u;
                out[(rowG + p) * N + col] = val;
                ((float*)&tp)[p] = val;
            }
            if (!diag) {
                *reinterpret_cast<float4*>(&out[col * (size_t)N + rowG]) = tp;
            }
        }
    }
}

extern "C" void kernel_launch(void* const* d_in, const int* in_sizes, int n_in,
                              void* d_out, int out_size, void* d_ws, size_t ws_size,
                              hipStream_t stream) {
    const float* X = (const float*)d_in[0];
    // d_in[1] = bandwidth_multipliers = 2^{-2..2}, folded analytically into the epilogue
    float* out = (float*)d_out;
    float* ws  = (float*)d_ws;

    prep_kernel<<<PB, 256, 0, stream>>>(X, ws);
    rbf_kernel<<<1024, 256, 0, stream>>>(X, ws, out);
}

// Round 5
// 85.658 us; speedup vs baseline: 1.1712x; 1.1712x over previous
//
#include <hip/hip_runtime.h>
#include <hip/hip_bf16.h>
#include <math.h>

#define N 4096
#define PB 32   // prep blocks / partial slots

typedef __attribute__((ext_vector_type(8))) short short8;
typedef __attribute__((ext_vector_type(4))) float floatx4;

// ws layout (floats): P[b*66 + d], b<32: d<64 = column-sum partials, [64] = sum(x^2) partial

__device__ inline unsigned bfpk(float a, float b) {
    unsigned ua = __float_as_uint(a), ub = __float_as_uint(b);
    ua = (ua + 0x7fffu + ((ua >> 16) & 1u)) >> 16;   // RNE fp32->bf16
    ub = (ub + 0x7fffu + ((ub >> 16) & 1u)) >> 16;
    return ua | (ub << 16);
}

__device__ inline uint4 pack8(float4 f0, float4 f1) {
    uint4 r;
    r.x = bfpk(f0.x, f0.y);
    r.y = bfpk(f0.z, f0.w);
    r.z = bfpk(f1.x, f1.y);
    r.w = bfpk(f1.z, f1.w);
    return r;
}

// ---------- prep: per-block partial column-sums + sum(x^2). No atomics, no init. ----------
__global__ __launch_bounds__(256) void prep_kernel(const float* __restrict__ X,
                                                   float* __restrict__ ws) {
    __shared__ float sm[256];
    __shared__ float ssum[4];
    const int lane = threadIdx.x & 63, w = threadIdx.x >> 6;
    const int b = blockIdx.x;
    const int row0 = b * 128 + w * 32;             // 32 rows per wave, 128 per block
    float mloc = 0.f, Sloc = 0.f;
    #pragma unroll
    for (int rr = 0; rr < 32; ++rr) {
        float x = X[(size_t)(row0 + rr) * 64 + lane];   // lane = column, coalesced
        mloc += x; Sloc += x * x;
    }
    sm[threadIdx.x] = mloc;
    #pragma unroll
    for (int off = 1; off < 64; off <<= 1) Sloc += __shfl_xor(Sloc, off, 64);
    if (lane == 0) ssum[w] = Sloc;
    __syncthreads();
    if (threadIdx.x < 64) {
        ws[b * 66 + threadIdx.x] =
            sm[threadIdx.x] + sm[64 + threadIdx.x] + sm[128 + threadIdx.x] + sm[192 + threadIdx.x];
    } else if (threadIdx.x == 64) {
        ws[b * 66 + 64] = ssum[0] + ssum[1] + ssum[2] + ssum[3];
    }
}

// ------------- main: symmetric half-tile MFMA gram + fused RBF epilogue (R3 grid) -------------
// Grid 1056. b<64: diagonal half d=b>>1, h=b&1 (direct stores only). b>=64: off-diag pair
// t=(b-64)>>1, h=(b-64)&1: direct (I,J) + transposed (J,I), BOTH float4 via dual products:
//   mfma(b_tj, a) -> lane holds rows R_{lr}, cols C_{tj16+q4+p}  (p-contig -> direct  float4)
//   mfma(a, b_tj) -> lane holds rows R_{q4+p}, cols C_{tj16+lr}  (p-contig -> transp. float4)
// LDS: slot(r,c) = 8*r + (c ^ (r&7)); fragment ds_read_b128 lands 2-way (free, m136).
__global__ __launch_bounds__(256) void rbf_kernel(const float* __restrict__ X,
                                                  const float* __restrict__ ws,
                                                  float* __restrict__ out) {
    __shared__ uint4 lA[512];    // 8 KB: 64 rows (off-diag I-half)
    __shared__ uint4 lB[1024];   // 16 KB: 128 rows (J-tile)
    __shared__ float sR[64];
    __shared__ float sC[128];

    const int t_ = threadIdx.x;
    const int b  = blockIdx.x;

    const bool diag = (b < 64);
    int I, J, h;
    if (diag) {
        I = J = b >> 1; h = b & 1;
    } else {
        int t = (b - 64) >> 1; h = (b - 64) & 1;
        int i = (int)((63.0f - sqrtf((float)(3969 - 8 * t))) * 0.5f);
        while (31 * (i + 1) - ((i + 1) * i) / 2 <= t) ++i;
        while (31 * i - (i * (i - 1)) / 2 > t) --i;
        int oi = 31 * i - (i * (i - 1)) / 2;
        I = i; J = i + 1 + (t - oi);
    }
    const int rowBase = I * 128 + h * 64;
    const int colBase = J * 128;

    // ---- stage fp32 -> bf16 into swizzled LDS; fold row norms in ----
    #pragma unroll
    for (int i = 0; i < 4; ++i) {       // J-tile: 128 rows
        int slot = i * 256 + t_;
        int r = slot >> 3, g = slot & 7;
        int c = g ^ (r & 7);
        const float4* p = (const float4*)(X + (size_t)(colBase + r) * 64 + c * 8);
        float4 f0 = p[0], f1 = p[1];
        lB[slot] = pack8(f0, f1);
        float nb = f0.x*f0.x + f0.y*f0.y + f0.z*f0.z + f0.w*f0.w
                 + f1.x*f1.x + f1.y*f1.y + f1.z*f1.z + f1.w*f1.w;
        #pragma unroll
        for (int off = 1; off < 8; off <<= 1) nb += __shfl_xor(nb, off, 64);
        if (g == 0) sC[r] = nb;
    }
    if (!diag) {
        #pragma unroll
        for (int i = 0; i < 2; ++i) {   // I-half: 64 rows
            int slot = i * 256 + t_;
            int r = slot >> 3, g = slot & 7;
            int c = g ^ (r & 7);
            const float4* p = (const float4*)(X + (size_t)(rowBase + r) * 64 + c * 8);
            float4 f0 = p[0], f1 = p[1];
            lA[slot] = pack8(f0, f1);
            float na = f0.x*f0.x + f0.y*f0.y + f0.z*f0.z + f0.w*f0.w
                     + f1.x*f1.x + f1.y*f1.y + f1.z*f1.z + f1.w*f1.w;
            #pragma unroll
            for (int off = 1; off < 8; off <<= 1) na += __shfl_xor(na, off, 64);
            if (g == 0) sR[r] = na;
        }
    }

    // ---- bw from prep partials (L2-resident 8.4 KB; overlaps staging, pre-barrier) ----
    const int lane = t_ & 63;
    float mv = 0.f;
    #pragma unroll 8
    for (int pb = 0; pb < PB; ++pb) mv += ws[pb * 66 + lane];
    float Sv = (lane < PB) ? ws[lane * 66 + 64] : 0.f;
    float mm = mv * mv;
    #pragma unroll
    for (int off = 1; off < 64; off <<= 1) {
        mm += __shfl_xor(mm, off, 64);
        Sv += __shfl_xor(Sv, off, 64);
    }
    float sumL2 = 2.0f * (float)N * Sv - 2.0f * mm;
    const float c1q = -1.4426950408889634f * 0.25f * (float)((size_t)N * N - N) / sumL2; // -log2e/(4*bw)

    __syncthreads();

    const int wave = t_ >> 6;
    const int lr = lane & 15, q = lane >> 4;
    const int rl = wave * 16 + lr;        // this wave's 16 local rows (within the 64-row half)

    // ---- A fragment: 16 rows of the row-strip ----
    short8 a0, a1;
    if (diag) {
        int rr = h * 64 + rl;
        a0 = *reinterpret_cast<const short8*>(&lB[8 * rr + ((q    ) ^ (rr & 7))]);
        a1 = *reinterpret_cast<const short8*>(&lB[8 * rr + ((q + 4) ^ (rr & 7))]);
    } else {
        a0 = *reinterpret_cast<const short8*>(&lA[8 * rl + ((q    ) ^ (rl & 7))]);
        a1 = *reinterpret_cast<const short8*>(&lA[8 * rl + ((q + 4) ^ (rl & 7))]);
    }
    const float rnorm = diag ? sC[h * 64 + rl] : sR[rl];

    // ================= phase A: direct float4 stores (ALL blocks) =================
    {
        floatx4 acc[8];
        #pragma unroll
        for (int tj = 0; tj < 8; ++tj) acc[tj] = (floatx4){0.f, 0.f, 0.f, 0.f};
        #pragma unroll
        for (int tj = 0; tj < 8; ++tj) {
            int r2 = tj * 16 + lr;
            short8 b0 = *reinterpret_cast<const short8*>(&lB[8 * r2 + ((q    ) ^ (r2 & 7))]);
            short8 b1 = *reinterpret_cast<const short8*>(&lB[8 * r2 + ((q + 4) ^ (r2 & 7))]);
            acc[tj] = __builtin_amdgcn_mfma_f32_16x16x32_bf16(b0, a0, acc[tj], 0, 0, 0);  // mirrored
            acc[tj] = __builtin_amdgcn_mfma_f32_16x16x32_bf16(b1, a1, acc[tj], 0, 0, 0);
        }
        float* orow = out + (size_t)(rowBase + rl) * N + colBase;
        #pragma unroll
        for (int tj = 0; tj < 8; ++tj) {
            int c0 = tj * 16 + q * 4;
            float4 v;
            #pragma unroll
            for (int p = 0; p < 4; ++p) {
                float d2 = rnorm + sC[c0 + p] - 2.0f * acc[tj][p];
                d2 = fmaxf(d2, 0.0f);
                float u  = __builtin_amdgcn_exp2f(d2 * c1q);   // t^(1/4)
                float s1 = u * u;
                float e  = s1 * s1;
                float e2 = e * e;
                float e4 = e2 * e2;
                ((float*)&v)[p] = e4 + e2 + e + s1 + u;
            }
            *reinterpret_cast<float4*>(orow + c0) = v;
        }
    }

    // ================= phase B: transposed float4 stores (off-diag only) =================
    if (!diag) {
        floatx4 acc[8];
        #pragma unroll
        for (int tj = 0; tj < 8; ++tj) acc[tj] = (floatx4){0.f, 0.f, 0.f, 0.f};
        #pragma unroll
        for (int tj = 0; tj < 8; ++tj) {
            int r2 = tj * 16 + lr;
            short8 b0 = *reinterpret_cast<const short8*>(&lB[8 * r2 + ((q    ) ^ (r2 & 7))]);
            short8 b1 = *reinterpret_cast<const short8*>(&lB[8 * r2 + ((q + 4) ^ (r2 & 7))]);
            acc[tj] = __builtin_amdgcn_mfma_f32_16x16x32_bf16(a0, b0, acc[tj], 0, 0, 0);  // normal
            acc[tj] = __builtin_amdgcn_mfma_f32_16x16x32_bf16(a1, b1, acc[tj], 0, 0, 0);
        }
        const int rb = wave * 16 + q * 4;
        float n0 = sR[rb], n1 = sR[rb + 1], n2 = sR[rb + 2], n3 = sR[rb + 3];
        #pragma unroll
        for (int tj = 0; tj < 8; ++tj) {
            int cl = tj * 16 + lr;
            float cn = sC[cl];
            float4 v;
            #pragma unroll
            for (int p = 0; p < 4; ++p) {
                float srp = (p == 0) ? n0 : (p == 1) ? n1 : (p == 2) ? n2 : n3;
                float d2 = srp + cn - 2.0f * acc[tj][p];
                d2 = fmaxf(d2, 0.0f);
                float u  = __builtin_amdgcn_exp2f(d2 * c1q);
                float s1 = u * u;
                float e  = s1 * s1;
                float e2 = e * e;
                float e4 = e2 * e2;
                ((float*)&v)[p] = e4 + e2 + e + s1 + u;
            }
            *reinterpret_cast<float4*>(out + (size_t)(colBase + cl) * N + rowBase + rb) = v;
        }
    }
}

extern "C" void kernel_launch(void* const* d_in, const int* in_sizes, int n_in,
                              void* d_out, int out_size, void* d_ws, size_t ws_size,
                              hipStream_t stream) {
    const float* X = (const float*)d_in[0];
    // d_in[1] = bandwidth_multipliers = 2^{-2..2}, folded analytically into the epilogue
    float* out = (float*)d_out;
    float* ws  = (float*)d_ws;

    prep_kernel<<<PB, 256, 0, stream>>>(X, ws);
    rbf_kernel<<<1056, 256, 0, stream>>>(X, ws, out);
}